// Round 1
// baseline (864.036 us; speedup 1.0000x reference)
//
#include <hip/hip_runtime.h>
#include <math.h>

// CapsNet fused forward. One block per batch image. All intermediates in LDS.
//
// Structure per block (b):
//   load x[b] (28x28) into LDS
//   for d in 0..7:                         // depth slice of primary caps
//     Phase A: conv1 channels c=i*8+d (i=0..31) -> LDS c1[32][20*20]
//     Phase B: prim conv (9x9 stride2, 32->32) on c1 -> u[n,d], folded
//              immediately into per-thread part[16] += u * dig_W[n,d,:]
//   reduce part[16] over block -> S, squash, 10x16 dense, softmax -> out[b,:]

#define BLOCK 256
#define C1_STRIDE 404   // 400 + 4 pad floats: breaks 16*i bank pattern, keeps 16B align

__global__ __launch_bounds__(BLOCK, 2) void capsnet_fused(
    const float* __restrict__ x,        // [B,1,28,28]
    const float* __restrict__ conv1_w,  // [256,1,9,9]
    const float* __restrict__ conv1_b,  // [256]
    const float* __restrict__ prim_w,   // [32,32,1,9,9]
    const float* __restrict__ prim_b,   // [32]
    const float* __restrict__ dig_W,    // [1152,8,16]
    const float* __restrict__ dig_Wb,   // [1152,16]
    const float* __restrict__ out_w,    // [10,10,16,1]
    const float* __restrict__ out_b,    // [10]
    float* __restrict__ out)            // [B,10]
{
    __shared__ __align__(16) float img[784];            // 28*28
    __shared__ __align__(16) float c1[32 * C1_STRIDE];  // 32 ch x (20*20 + pad)
    __shared__ float red[16];
    __shared__ float lgts[10];

    const int b = blockIdx.x;
    const int t = threadIdx.x;

    // ---- load image ----
    for (int j = t; j < 784; j += BLOCK) img[j] = x[b * 784 + j];
    if (t < 16) red[t] = 0.f;

    // per-thread accumulator for S (before /1152)
    float part[16];
#pragma unroll
    for (int k = 0; k < 16; ++k) part[k] = 0.f;

    // ---- dig_Wb contribution: sum_n dig_Wb[n,dd] ----
    {
        const int dd = t & 15, chunk = t >> 4;   // 16 chunks x 72 n
        float s = 0.f;
        for (int j = 0; j < 72; ++j) s += dig_Wb[(chunk * 72 + j) * 16 + dd];
#pragma unroll
        for (int k = 0; k < 16; ++k) if (k == dd) part[k] += s;
    }

    __syncthreads();

    for (int d = 0; d < 8; ++d) {
        // ======== Phase A: conv1 slice (channels i*8+d) ========
        // task tau: i = tau&31 (channel group), y = tau>>5 (output row), 20 outputs
        for (int tau = t; tau < 640; tau += BLOCK) {
            const int i = tau & 31, y = tau >> 5;
            const int c = i * 8 + d;
            float acc[20];
#pragma unroll
            for (int xx = 0; xx < 20; ++xx) acc[xx] = 0.f;
            for (int ky = 0; ky < 9; ++ky) {
                float r[28];
                const float4* prow = (const float4*)&img[(y + ky) * 28];
#pragma unroll
                for (int m = 0; m < 7; ++m) {
                    float4 v = prow[m];
                    r[m * 4 + 0] = v.x; r[m * 4 + 1] = v.y;
                    r[m * 4 + 2] = v.z; r[m * 4 + 3] = v.w;
                }
                const float* wr = &conv1_w[c * 81 + ky * 9];
#pragma unroll
                for (int kx = 0; kx < 9; ++kx) {
                    const float w = wr[kx];
#pragma unroll
                    for (int xx = 0; xx < 20; ++xx)
                        acc[xx] = fmaf(r[xx + kx], w, acc[xx]);
                }
            }
            const float bias = conv1_b[c];
            float4* crow = (float4*)&c1[i * C1_STRIDE + y * 20];
#pragma unroll
            for (int m = 0; m < 5; ++m) {
                float4 v;
                v.x = fmaxf(acc[m * 4 + 0] + bias, 0.f);
                v.y = fmaxf(acc[m * 4 + 1] + bias, 0.f);
                v.z = fmaxf(acc[m * 4 + 2] + bias, 0.f);
                v.w = fmaxf(acc[m * 4 + 3] + bias, 0.f);
                crow[m] = v;
            }
        }
        __syncthreads();

        // ======== Phase B: prim conv + dig_W fold ========
        // task t<192: o = t/6 (out channel), h = t%6 (out row), 6 outputs (w)
        if (t < 192) {
            const int o = t / 6, h = t % 6;
            float acc6[6];
#pragma unroll
            for (int w = 0; w < 6; ++w) acc6[w] = 0.f;
            for (int i = 0; i < 32; ++i) {
                for (int ky = 0; ky < 9; ++ky) {
                    float r[20];
                    const float4* prow =
                        (const float4*)&c1[i * C1_STRIDE + (2 * h + ky) * 20];
#pragma unroll
                    for (int m = 0; m < 5; ++m) {
                        float4 v = prow[m];
                        r[m * 4 + 0] = v.x; r[m * 4 + 1] = v.y;
                        r[m * 4 + 2] = v.z; r[m * 4 + 3] = v.w;
                    }
                    const float* wr = &prim_w[(o * 32 + i) * 81 + ky * 9];
#pragma unroll
                    for (int kx = 0; kx < 9; ++kx) {
                        const float w = wr[kx];
#pragma unroll
                        for (int ww = 0; ww < 6; ++ww)
                            acc6[ww] = fmaf(r[2 * ww + kx], w, acc6[ww]);
                    }
                }
            }
            const float pb = prim_b[o];
#pragma unroll
            for (int ww = 0; ww < 6; ++ww) {
                const float val = fmaxf(acc6[ww] + pb, 0.f);
                const int n = o * 36 + ww * 6 + h;   // n = c*36 + w*6 + h
                const float4* wd = (const float4*)&dig_W[n * 128 + d * 16];
#pragma unroll
                for (int m = 0; m < 4; ++m) {
                    float4 v = wd[m];
                    part[m * 4 + 0] = fmaf(val, v.x, part[m * 4 + 0]);
                    part[m * 4 + 1] = fmaf(val, v.y, part[m * 4 + 1]);
                    part[m * 4 + 2] = fmaf(val, v.z, part[m * 4 + 2]);
                    part[m * 4 + 3] = fmaf(val, v.w, part[m * 4 + 3]);
                }
            }
        }
        __syncthreads();   // protect c1 before next Phase A overwrites
    }

    // ---- block-wide reduction of part[16] ----
#pragma unroll
    for (int k = 0; k < 16; ++k) {
        float v = part[k];
        v += __shfl_down(v, 32, 64);
        v += __shfl_down(v, 16, 64);
        v += __shfl_down(v, 8, 64);
        v += __shfl_down(v, 4, 64);
        v += __shfl_down(v, 2, 64);
        v += __shfl_down(v, 1, 64);
        if ((t & 63) == 0) atomicAdd(&red[k], v);
    }
    __syncthreads();

    // ---- squash + 10x16 dense (threads 0..9, one logit each) ----
    if (t < 10) {
        float S[16];
        float l2 = 0.f, l1 = 0.f;
#pragma unroll
        for (int k = 0; k < 16; ++k) {
            S[k] = red[k] * (1.f / 1152.f);
            l2 += S[k] * S[k];
            l1 += fabsf(S[k]);
        }
        l2 = sqrtf(l2);
        const float sc = l2 / (1.f + l2) / l1;
        float lg = out_b[t];
        for (int i2 = 0; i2 < 10; ++i2) {
            const float* wrow = &out_w[(t * 10 + i2) * 16];
#pragma unroll
            for (int k = 0; k < 16; ++k)
                lg = fmaf(S[k] * sc, wrow[k], lg);
        }
        lgts[t] = lg;
    }
    __syncthreads();

    // ---- softmax over 10 ----
    if (t < 10) {
        float mx = -1e30f;
#pragma unroll
        for (int o = 0; o < 10; ++o) mx = fmaxf(mx, lgts[o]);
        float sum = 0.f;
#pragma unroll
        for (int o = 0; o < 10; ++o) sum += expf(lgts[o] - mx);
        out[b * 10 + t] = expf(lgts[t] - mx) / sum;
    }
}

extern "C" void kernel_launch(void* const* d_in, const int* in_sizes, int n_in,
                              void* d_out, int out_size, void* d_ws, size_t ws_size,
                              hipStream_t stream) {
    const float* x       = (const float*)d_in[0];
    const float* conv1_w = (const float*)d_in[1];
    const float* conv1_b = (const float*)d_in[2];
    const float* prim_w  = (const float*)d_in[3];
    const float* prim_b  = (const float*)d_in[4];
    const float* dig_W   = (const float*)d_in[5];
    const float* dig_Wb  = (const float*)d_in[6];
    const float* out_w   = (const float*)d_in[7];
    const float* out_b   = (const float*)d_in[8];
    float* out = (float*)d_out;

    const int B = in_sizes[0] / 784;   // 512
    capsnet_fused<<<B, BLOCK, 0, stream>>>(x, conv1_w, conv1_b, prim_w, prim_b,
                                           dig_W, dig_Wb, out_w, out_b, out);
}